// Round 2
// baseline (444.146 us; speedup 1.0000x reference)
//
#include <hip/hip_runtime.h>
#include <math.h>

// Cyborg stack machine: B=256, S=128, V=512, H=30, N_STACKS=2, R=2, DEPTH=4
// All stack/peek/output vectors live in span{ones, init_vec, syms0..29} (32-dim).
// kA (R6): split-f16 MFMA GEMM (x=xh+xl, w=wh+wl; 3 MFMAs; fp32-grade precision).
// kC (R7 redesign): latency-bound serial scan -> 2 barriers/step (was 4).
//   - iq (Gram norm) computed redundantly per-wave (Mr in all waves, butterfly
//     reduce) -> no iqL publish, no B3.
//   - wave3 computes out-coords via shuffles over its in-register nnd2 -> no
//     nnd2L publish, no B4/region E.
//   - phase-1-next dots (rows) and phase-2-current dots (wave3) run in the same
//     region concurrently; dot chains split into 2 partials for ILP.

#define SS 128
#define VV 512
#define NROWS 208      // 8 pop + 8 pushop + 128 pushfn + 64 calc
#define ZOFF 1e-6f

// ws layout (float offsets)
#define OFF_I0   0                          // interp0: 32768*208
#define OFF_OC   (32768*208)                // out coords: 32768*32
#define OFF_GI   (OFF_OC + 32768*32)        // G[2][32][208]  (stack, basis, row)
#define OFF_M    (OFF_GI + 2*32*208)        // Gram 32*32
#define OFF_A    (OFF_M + 1024)             // A coef 208*3
#define OFF_Bc   (OFF_A + 624)              // B coef 208*3
#define OFF_W0   (OFF_Bc + 624)             // Wh/Wl f16: 2 x [208][512] halves

typedef _Float16 half8 __attribute__((ext_vector_type(8)));
typedef float f32x4 __attribute__((ext_vector_type(4)));

__device__ __forceinline__ const float* w_row(int r, const float* pw, const float* pow_,
                                              const float* pfw, const float* cw) {
    if (r < 8)   return pw   + r * 1536;
    if (r < 16)  return pow_ + (r - 8) * 1536;
    if (r < 144) return pfw  + (r - 16) * 1536;
    return cw + (r - 144) * 1536;
}
__device__ __forceinline__ const float* nw_row(int r, const float* pn, const float* pon,
                                               const float* pfn, const float* cn) {
    if (r < 8)   return pn   + r * 3;
    if (r < 16)  return pon  + (r - 8) * 3;
    if (r < 144) return pfn  + (r - 16) * 3;
    return cn + (r - 144) * 3;
}

// ---------------- kernel B: precompute tables ----------------
__global__ void kB(const float* __restrict__ syms, const float* __restrict__ siv,
                   const float* __restrict__ pw, const float* __restrict__ pn,
                   const float* __restrict__ pow_, const float* __restrict__ pon,
                   const float* __restrict__ pfw, const float* __restrict__ pfn,
                   const float* __restrict__ cw, const float* __restrict__ cn,
                   float* __restrict__ ws) {
    int blk = blockIdx.x, tid = threadIdx.x;
    if (blk < 64) {
        // G[jj][e][c] = basis_e . w_row(c)[(jj+1)*512 ..)
        int jj = blk >> 5, e = blk & 31;
        __shared__ float bas[512];
        for (int i = tid; i < 512; i += 256)
            bas[i] = (e == 0) ? 1.0f : ((e == 1) ? siv[i] : syms[(e - 2) * 512 + i]);
        __syncthreads();
        if (tid < NROWS) {
            int c = tid;
            const float4* w4 = (const float4*)(w_row(c, pw, pow_, pfw, cw) + (jj + 1) * 512);
            const float4* b4 = (const float4*)bas;
            float s = 0.f;
            for (int q = 0; q < 128; ++q) {
                float4 a = b4[q], b = w4[q];
                s += a.x * b.x + a.y * b.y + a.z * b.z + a.w * b.w;
            }
            ws[OFF_GI + (jj * 32 + e) * 208 + c] = s;
        }
    } else if (blk == 64) {
        // Gram M[m][mm]
        __shared__ float basw[32 * 512];
        for (int i = tid; i < 32 * 512; i += 256) {
            int m = i >> 9, v = i & 511;
            basw[i] = (m == 0) ? 1.0f : ((m == 1) ? siv[v] : syms[(m - 2) * 512 + v]);
        }
        __syncthreads();
        for (int p = tid; p < 1024; p += 256) {
            int m = p >> 5, mm = p & 31;
            const float4* a4 = (const float4*)(basw + m * 512);
            const float4* b4 = (const float4*)(basw + mm * 512);
            float s = 0.f;
            for (int q = 0; q < 128; ++q) {
                float4 a = a4[q], b = b4[q];
                s += a.x * b.x + a.y * b.y + a.z * b.z + a.w * b.w;
            }
            ws[OFF_M + p] = s;
        }
    } else if (blk == 65) {
        // folded NAND coefs: A=(2*sig-1)/||w||, B=1-sig   for (r, j)
        for (int idx = tid; idx < 624; idx += 256) {
            int r = idx / 3, j = idx % 3;
            const float4* w4 = (const float4*)(w_row(r, pw, pow_, pfw, cw) + j * 512);
            float s = 0.f;
            for (int q = 0; q < 128; ++q) {
                float4 b = w4[q];
                s += b.x * b.x + b.y * b.y + b.z * b.z + b.w * b.w;
            }
            float nrm = fmaxf(sqrtf(s), 1e-8f);
            float nwv = nw_row(r, pn, pon, pfn, cn)[j];
            float sig = 1.f / (1.f + expf(-nwv));
            ws[OFF_A + idx]  = (2.f * sig - 1.f) / nrm;
            ws[OFF_Bc + idx] = 1.f - sig;
        }
    } else {
        // gather w j=0 slice as split-f16 hi/lo: Wh/Wl [208][512] halves — 16 blocks
        int part = blk - 66;
        _Float16* whp = (_Float16*)(ws + OFF_W0);
        _Float16* wlp = whp + 208 * 512;
        for (int i = tid; i < 6656; i += 256) {
            int flat = part * 6656 + i;
            int c = flat >> 9, v = flat & 511;
            float wv = w_row(c, pw, pow_, pfw, cw)[v];
            _Float16 h = (_Float16)wv;
            whp[flat] = h;
            wlp[flat] = (_Float16)(wv - (float)h);
        }
    }
}

// ---------------- kernel A: interp0 via split-f16 MFMA GEMM ----------------
__global__ __launch_bounds__(256) void kA(const float* __restrict__ x, float* __restrict__ ws) {
    __shared__ half8 AH[2][256];   // [buf][mfrag*64 + fraglane]
    __shared__ half8 AL[2][256];
    __shared__ float red[256];
    __shared__ float invx[64];
    const int tid = threadIdx.x;
    const int wid = tid >> 6, l = tid & 63;
    const size_t bt0 = (size_t)blockIdx.x * 64;

    const int sr = tid >> 2, ss = tid & 3;
    const float* xp = x + (bt0 + sr) * 512 + ss * 8;
    const int wpos = (sr >> 4) * 64 + (sr & 15) + (ss << 4);   // frag slot

    const _Float16* whp = (const _Float16*)(ws + OFF_W0);
    const _Float16* wlp = whp + 208 * 512;

    const int t0 = (wid == 0) ? 0 : (1 + 3 * wid);   // 0,4,7,10
    const int nt = (wid == 0) ? 4 : 3;

    f32x4 acc[4][4];
#pragma unroll
    for (int m = 0; m < 4; ++m)
#pragma unroll
        for (int tt = 0; tt < 4; ++tt)
            acc[m][tt] = (f32x4){0.f, 0.f, 0.f, 0.f};

    float sumsq = 0.f;
    auto stage = [&](int kt, int buf) {
        float v[8];
        *(float4*)v       = *(const float4*)(xp + kt * 32);
        *(float4*)(v + 4) = *(const float4*)(xp + kt * 32 + 4);
        half8 hh, hl;
#pragma unroll
        for (int j = 0; j < 8; ++j) {
            sumsq += v[j] * v[j];
            _Float16 h = (_Float16)v[j];
            hh[j] = h;
            hl[j] = (_Float16)(v[j] - (float)h);
        }
        AH[buf][wpos] = hh;
        AL[buf][wpos] = hl;
    };

    stage(0, 0);
    __syncthreads();

    for (int kt = 0; kt < 16; ++kt) {
        const int buf = kt & 1;
        if (kt < 15) stage(kt + 1, buf ^ 1);

        half8 ahm[4], alm[4];
#pragma unroll
        for (int m = 0; m < 4; ++m) {
            ahm[m] = AH[buf][m * 64 + l];
            alm[m] = AL[buf][m * 64 + l];
        }
        const int kof = kt * 32 + (l >> 4) * 8;
#pragma unroll
        for (int tt = 0; tt < 4; ++tt) {
            if (tt < nt) {
                const int c = (t0 + tt) * 16 + (l & 15);
                half8 bh = *(const half8*)(whp + c * 512 + kof);
                half8 bl = *(const half8*)(wlp + c * 512 + kof);
#pragma unroll
                for (int m = 0; m < 4; ++m) {
                    acc[m][tt] = __builtin_amdgcn_mfma_f32_16x16x32_f16(ahm[m], bh, acc[m][tt], 0, 0, 0);
                    acc[m][tt] = __builtin_amdgcn_mfma_f32_16x16x32_f16(ahm[m], bl, acc[m][tt], 0, 0, 0);
                    acc[m][tt] = __builtin_amdgcn_mfma_f32_16x16x32_f16(alm[m], bh, acc[m][tt], 0, 0, 0);
                }
            }
        }
        __syncthreads();
    }

    red[tid] = sumsq;
    __syncthreads();
    if (tid < 64) {
        float s = red[tid * 4] + red[tid * 4 + 1] + red[tid * 4 + 2] + red[tid * 4 + 3];
        invx[tid] = 1.f / fmaxf(sqrtf(s), 1e-8f);
    }
    __syncthreads();

    // epilogue: interp0 = A0*|dot|*invx + B0.  D frag: col=lane&15, row=(lane>>4)*4+reg
#pragma unroll
    for (int tt = 0; tt < 4; ++tt) {
        if (tt < nt) {
            const int c = (t0 + tt) * 16 + (l & 15);
            const float A0 = ws[OFF_A + c * 3];
            const float B0 = ws[OFF_Bc + c * 3];
#pragma unroll
            for (int m = 0; m < 4; ++m) {
                const int rbase = m * 16 + (l >> 4) * 4;
#pragma unroll
                for (int j = 0; j < 4; ++j) {
                    const float ix = invx[rbase + j];
                    ws[OFF_I0 + (bt0 + rbase + j) * 208 + c] = A0 * fabsf(acc[m][tt][j]) * ix + B0;
                }
            }
        }
    }
}

// ---------------- kernel C: serial scan, 2 barriers/step ----------------
// tid 0..143: phase-1 row tid (G1[64] in regs). wave3: calc row 144+l (G2[64]).
// ALL waves: replicated stack state + Mr[32] for redundant Gram/iq.
// Loop: gates+update -> pkL' publish -> B2 -> [rows: iq', dots1, nnd(t+1) ->
// nndL | wave3: iq', dots2, nnd2(t), shuffle -> oc(t) store] -> B1.
__global__ __attribute__((amdgpu_flat_work_group_size(256, 256), amdgpu_waves_per_eu(1, 1)))
void kC(float* __restrict__ ws, const float* __restrict__ sharp) {
    __shared__ float pkL[64];
    __shared__ float nndL[144];
    const int b = blockIdx.x, tid = threadIdx.x;
    const int wid = tid >> 6, l = tid & 63;
    const int k = l >> 5, m = l & 31;
    const int isRow = (tid < 144);
    const int r2 = 144 + l;            // wave3's calc row

    const float* GI = ws + OFF_GI;
    float G1[64], G2[64];
    float4 Mr[8];
    float A1r = 0.f, A2r = 0.f, B1r = 0.f, B2r = 0.f;
    float A1d = 0.f, A2d = 0.f, B1d = 0.f, B2d = 0.f;
    if (isRow) {
#pragma unroll
        for (int i = 0; i < 32; ++i) {
            G1[i]      = GI[i * 208 + tid];
            G1[32 + i] = GI[(32 + i) * 208 + tid];
        }
        A1r = ws[OFF_A + tid * 3 + 1];  A2r = ws[OFF_A + tid * 3 + 2];
        B1r = ws[OFF_Bc + tid * 3 + 1]; B2r = ws[OFF_Bc + tid * 3 + 2];
    }
    if (wid == 3) {
#pragma unroll
        for (int i = 0; i < 32; ++i) {
            G2[i]      = GI[i * 208 + r2];
            G2[32 + i] = GI[(32 + i) * 208 + r2];
        }
        A1d = ws[OFF_A + r2 * 3 + 1];  A2d = ws[OFF_A + r2 * 3 + 2];
        B1d = ws[OFF_Bc + r2 * 3 + 1]; B2d = ws[OFF_Bc + r2 * 3 + 2];
    }
    // ALL waves hold the Gram row for their m
#pragma unroll
    for (int q = 0; q < 8; ++q) Mr[q] = *(const float4*)(ws + OFF_M + m * 32 + q * 4);

    const float sh = sharp[k];

    // replicated stack state
    float st[4], p[4];
#pragma unroll
    for (int d = 0; d < 4; ++d) {
        st[d] = (d == 1) ? ((m == 1) ? 1.f : 0.f) : ((m == 0) ? ZOFF : 0.f);
        p[d] = (d == 1) ? 1.f : 0.f;
    }
    float pk = st[0] * p[0] + st[1] * p[1] + st[2] * p[2] + st[3] * p[3];

    const float* i0base = ws + OFF_I0 + (size_t)b * SS * 208;
    float i0r  = isRow ? i0base[tid] : 0.f;        // i0(0)
    float i0rn = 0.f;                               // i0(t+1) in flight
    float i0d  = (wid == 3) ? i0base[r2] : 0.f;    // i0d(0)

    float iq0 = 1.f, iq1 = 1.f;
    // redundant per-wave Gram -> iq0/iq1 from pkL (+ own component `own`)
    auto gram_iq = [&](float own) {
        const float* ph = pkL + 32 * k;
        float4 a0 = *(const float4*)(ph);
        float4 a1 = *(const float4*)(ph + 4);
        float4 a2 = *(const float4*)(ph + 8);
        float4 a3 = *(const float4*)(ph + 12);
        float4 a4 = *(const float4*)(ph + 16);
        float4 a5 = *(const float4*)(ph + 20);
        float4 a6 = *(const float4*)(ph + 24);
        float4 a7 = *(const float4*)(ph + 28);
        float mva = Mr[0].x*a0.x + Mr[0].y*a0.y + Mr[0].z*a0.z + Mr[0].w*a0.w
                  + Mr[2].x*a2.x + Mr[2].y*a2.y + Mr[2].z*a2.z + Mr[2].w*a2.w
                  + Mr[4].x*a4.x + Mr[4].y*a4.y + Mr[4].z*a4.z + Mr[4].w*a4.w
                  + Mr[6].x*a6.x + Mr[6].y*a6.y + Mr[6].z*a6.z + Mr[6].w*a6.w;
        float mvb = Mr[1].x*a1.x + Mr[1].y*a1.y + Mr[1].z*a1.z + Mr[1].w*a1.w
                  + Mr[3].x*a3.x + Mr[3].y*a3.y + Mr[3].z*a3.z + Mr[3].w*a3.w
                  + Mr[5].x*a5.x + Mr[5].y*a5.y + Mr[5].z*a5.z + Mr[5].w*a5.w
                  + Mr[7].x*a7.x + Mr[7].y*a7.y + Mr[7].z*a7.z + Mr[7].w*a7.w;
        float part = own * (mva + mvb);
        part += __shfl_xor(part, 1);  part += __shfl_xor(part, 2);
        part += __shfl_xor(part, 4);  part += __shfl_xor(part, 8);
        part += __shfl_xor(part, 16);
        float iqOwn = 1.f / fmaxf(sqrtf(part), 1e-8f);
        float iqOth = __shfl_xor(iqOwn, 32);
        iq0 = k ? iqOth : iqOwn;
        iq1 = k ? iqOwn : iqOth;
    };
    // split-chain dot of pkL against a 64-entry register table
    auto dots = [&](const float* Gt, float& d1, float& d2) {
        float d1a = 0.f, d1b = 0.f, d2a = 0.f, d2b = 0.f;
#pragma unroll
        for (int q = 0; q < 8; q += 2) {
            float4 a = *(const float4*)(pkL + 4 * q);
            float4 bq = *(const float4*)(pkL + 4 * q + 4);
            float4 c = *(const float4*)(pkL + 32 + 4 * q);
            float4 e = *(const float4*)(pkL + 32 + 4 * q + 4);
            d1a += a.x * Gt[4*q]   + a.y * Gt[4*q+1]   + a.z * Gt[4*q+2]   + a.w * Gt[4*q+3];
            d1b += bq.x * Gt[4*q+4] + bq.y * Gt[4*q+5] + bq.z * Gt[4*q+6] + bq.w * Gt[4*q+7];
            d2a += c.x * Gt[32+4*q] + c.y * Gt[33+4*q] + c.z * Gt[34+4*q] + c.w * Gt[35+4*q];
            d2b += e.x * Gt[36+4*q] + e.y * Gt[37+4*q] + e.z * Gt[38+4*q] + e.w * Gt[39+4*q];
        }
        d1 = d1a + d1b;
        d2 = d2a + d2b;
    };

    // ---- prologue: publish pk(0), iq(0), nnd(0) ----
    if (wid == 0) pkL[l] = pk;
    __syncthreads();
    gram_iq(pk);
    if (isRow) {
        float d1, d2;
        dots(G1, d1, d2);
        nndL[tid] = i0r * (A1r * fabsf(d1) * iq0 + B1r) * (A2r * fabsf(d2) * iq1 + B2r);
        i0rn = i0base[208 + tid];   // i0(1)
    }
    __syncthreads();

    for (int t = 0; t < SS; ++t) {
        // ---- region B: gates + push_val + state update (replicated) ----
        float4 gp4 = *(const float4*)(nndL + 4 * k);
        float4 gq4 = *(const float4*)(nndL + 8 + 4 * k);
        float prp0 = 1.f / (1.f + __expf((fmaxf(gp4.z, gp4.w) - fmaxf(gp4.x, gp4.y)) * sh));
        float prq0 = 1.f / (1.f + __expf((fmaxf(gq4.z, gq4.w) - fmaxf(gq4.x, gq4.y)) * sh));
        float prp1 = 1.f - prp0, prq1 = 1.f - prq0;
        float prx = 0.f, pry = 0.f;
        if (m >= 2) {
            float2 pr2 = *(const float2*)(nndL + 16 + 64 * k + 2 * m - 4);
            prx = pr2.x; pry = pr2.y;
        }
        float4 t30 = *(const float4*)(nndL + 16 + 64 * k + 60);
        float pkOther = __shfl_xor(pk, 32);
        float pk0m = k ? pkOther : pk;
        float pk1m = k ? pk : pkOther;
        float pvc = prx + pry + (t30.x + t30.y) * pk0m + (t30.z + t30.w) * pk1m;

        float zc = (m == 0) ? ZOFF : 0.f;
        float s1[4], p1[4];
#pragma unroll
        for (int d = 0; d < 4; ++d) {
            float ps = st[d] * (1.f - p[d]) + zc * p[d];
            s1[d] = ps * prp0 + st[d] * prp1;
            p1[d] = p[(d + 1) & 3] * prp0 + p[d] * prp1;
        }
#pragma unroll
        for (int d = 0; d < 4; ++d) {
            float pu = p1[(d + 3) & 3];
            float su = s1[d] * (1.f - pu) + pvc * pu;
            st[d] = su * prq0 + s1[d] * prq1;
            p[d] = pu * prq0 + p1[d] * prq1;
        }
        float pkp = st[0] * p[0] + st[1] * p[1] + st[2] * p[2] + st[3] * p[3];
        if (wid == 0) pkL[l] = pkp;
        __syncthreads();   // B2: pkL' visible

        // ---- region CA: everything from pk' in one region ----
        gram_iq(pkp);      // iq'(t) = iq(t+1), all waves, butterfly-local
        if (isRow) {
            float d1, d2;
            dots(G1, d1, d2);
            float iv = i0rn;                                   // i0(t+1)
            int tn2 = (t < SS - 2) ? (t + 2) : (SS - 1);
            i0rn = i0base[(size_t)tn2 * 208 + tid];            // prefetch i0(t+2)
            nndL[tid] = iv * (A1r * fabsf(d1) * iq0 + B1r) * (A2r * fabsf(d2) * iq1 + B2r);
        }
        if (wid == 3) {
            float dd1, dd2;
            dots(G2, dd1, dd2);
            float nnd2 = i0d * (A1d * fabsf(dd1) * iq0 + B1d) * (A2d * fabsf(dd2) * iq1 + B2d);
            int tn = (t < SS - 1) ? (t + 1) : (SS - 1);
            i0d = i0base[(size_t)tn * 208 + r2];               // prefetch i0d(t+1)
            // out coords via shuffles over per-lane nnd2 (calc row 144+lane)
            int src = (m >= 2) ? (2 * m - 4) : 0;
            float cx = __shfl(nnd2, src);
            float cy = __shfl(nnd2, src + 1);
            if (m < 2) { cx = 0.f; cy = 0.f; }
            float s60 = __shfl(nnd2, 60), s61 = __shfl(nnd2, 61);
            float s62 = __shfl(nnd2, 62), s63 = __shfl(nnd2, 63);
            float pkpO = __shfl_xor(pkp, 32);
            if (l < 32) {
                float oc = cx + cy + (s60 + s61) * pkp + (s62 + s63) * pkpO;
                ws[OFF_OC + ((size_t)b * SS + t) * 32 + m] = oc;
            }
        }
        __syncthreads();   // B1: nndL(t+1) visible
        pk = pkp;
    }
}

// ---------------- kernel D: expand coords -> 512-dim output (barrier-free) ----------------
__global__ __launch_bounds__(256) void kD(const float* __restrict__ ws, const float* __restrict__ syms,
                                          const float* __restrict__ siv, float* __restrict__ out) {
    int t = threadIdx.x;
    int rg = t >> 6;
    int vc = (t & 63) * 8;
    size_t r0 = (size_t)blockIdx.x * 16 + rg * 4;
    const float* oc = ws + OFF_OC;
    float acc[4][8];
    float4 sv0 = *(const float4*)(siv + vc);
    float4 sv1 = *(const float4*)(siv + vc + 4);
#pragma unroll
    for (int rr = 0; rr < 4; ++rr) {
        float c0 = oc[(r0 + rr) * 32 + 0];
        float c1 = oc[(r0 + rr) * 32 + 1];
        acc[rr][0] = c0 + c1 * sv0.x; acc[rr][1] = c0 + c1 * sv0.y;
        acc[rr][2] = c0 + c1 * sv0.z; acc[rr][3] = c0 + c1 * sv0.w;
        acc[rr][4] = c0 + c1 * sv1.x; acc[rr][5] = c0 + c1 * sv1.y;
        acc[rr][6] = c0 + c1 * sv1.z; acc[rr][7] = c0 + c1 * sv1.w;
    }
    for (int mm = 0; mm < 30; ++mm) {
        float4 b0 = *(const float4*)(syms + mm * 512 + vc);
        float4 b1 = *(const float4*)(syms + mm * 512 + vc + 4);
#pragma unroll
        for (int rr = 0; rr < 4; ++rr) {
            float c = oc[(r0 + rr) * 32 + 2 + mm];
            acc[rr][0] += c * b0.x; acc[rr][1] += c * b0.y;
            acc[rr][2] += c * b0.z; acc[rr][3] += c * b0.w;
            acc[rr][4] += c * b1.x; acc[rr][5] += c * b1.y;
            acc[rr][6] += c * b1.z; acc[rr][7] += c * b1.w;
        }
    }
#pragma unroll
    for (int rr = 0; rr < 4; ++rr) {
        float* o = out + (r0 + rr) * 512 + vc;
        *(float4*)o       = make_float4(acc[rr][0], acc[rr][1], acc[rr][2], acc[rr][3]);
        *(float4*)(o + 4) = make_float4(acc[rr][4], acc[rr][5], acc[rr][6], acc[rr][7]);
    }
}

extern "C" void kernel_launch(void* const* d_in, const int* in_sizes, int n_in,
                              void* d_out, int out_size, void* d_ws, size_t ws_size,
                              hipStream_t stream) {
    const float* x    = (const float*)d_in[0];
    const float* syms = (const float*)d_in[1];
    const float* siv  = (const float*)d_in[2];
    const float* shp  = (const float*)d_in[3];
    const float* pw   = (const float*)d_in[4];
    const float* pn   = (const float*)d_in[5];
    const float* pow_ = (const float*)d_in[6];
    const float* pon  = (const float*)d_in[7];
    const float* pfw  = (const float*)d_in[8];
    const float* pfn  = (const float*)d_in[9];
    const float* cw   = (const float*)d_in[10];
    const float* cn   = (const float*)d_in[11];
    float* ws  = (float*)d_ws;
    float* out = (float*)d_out;

    hipLaunchKernelGGL(kB, dim3(82),   dim3(256), 0, stream,
                       syms, siv, pw, pn, pow_, pon, pfw, pfn, cw, cn, ws);
    hipLaunchKernelGGL(kA, dim3(512),  dim3(256), 0, stream, x, ws);
    hipLaunchKernelGGL(kC, dim3(256),  dim3(256), 0, stream, ws, shp);
    hipLaunchKernelGGL(kD, dim3(2048), dim3(256), 0, stream, ws, syms, siv, out);
}